// Round 1
// 221.529 us; speedup vs baseline: 1.0127x; 1.0127x over previous
//
#include <hip/hip_runtime.h>

#define BATCH 16
#define CIN   64
#define HW    128
#define OC    128
#define KSIZE 576   // 64 * 9

typedef float float4v __attribute__((ext_vector_type(4)));
typedef int   int4v   __attribute__((ext_vector_type(4)));
typedef unsigned int uint;

// workspace layout (float offsets)
#define WS_ACT   0      // act_scale[576], k = c*9 + r order
#define WS_WSC   576    // weight_scale[576]
#define WS_XMUL  1152   // xmul[r*64+c] = 1/(scale[c*9+r]*s_x)
#define WS_SXSW  1728
#define WS_WQ_BYTE_OFF 8192   // int8 wq_s[9][128][64], frags XOR-pre-swizzled

#define SWZ(x) ((((x) & 3) ^ (((x) >> 2) & 3)))
#define MAGIC 12582912.0f   // 1.5 * 2^23: fma bias => round-half-even int8 in low byte

__device__ __forceinline__ void async_cp16(const void* g, void* l) {
    __builtin_amdgcn_global_load_lds(
        (const __attribute__((address_space(1))) unsigned int*)g,
        (__attribute__((address_space(3))) unsigned int*)l, 16, 0, 0);
}

// ---------------------------------------------------------------------------
// Kernel 1: fused absmax (unchanged — validated R2-R4).
// ---------------------------------------------------------------------------
__global__ __launch_bounds__(256) void k_absmax(const float* __restrict__ in,
                                                const float* __restrict__ w,
                                                float* __restrict__ wsf) {
    const int tid = threadIdx.x, lane = tid & 63, wid = tid >> 6;
    if (blockIdx.x < 1024) {
        const int c = blockIdx.x >> 4, bs = blockIdx.x & 15;
        const float4v* p = (const float4v*)(in + (size_t)(bs * CIN + c) * (HW * HW));
        float m[9];
#pragma unroll
        for (int i = 0; i < 9; ++i) m[i] = 0.f;
        for (int e = tid; e < 4096; e += 256) {
            const int h = e >> 5, q = e & 31;
            const float4v v = p[e];
            const float a0 = fabsf(v[0]), a1 = fabsf(v[1]), a2 = fabsf(v[2]), a3 = fabsf(v[3]);
            const float m01 = fmaxf(a0, a1), m12 = fmaxf(a1, a2);
            const float mall = fmaxf(m01, fmaxf(a2, a3));
            const float mw0 = (q == 31) ? fmaxf(m01, a2) : mall;
            const float mw2 = (q == 0)  ? fmaxf(m12, a3) : mall;
            const bool h0 = (h <= 126), h2 = (h >= 1);
            m[0] = fmaxf(m[0], h0 ? mw0 : 0.f);
            m[1] = fmaxf(m[1], h0 ? mall : 0.f);
            m[2] = fmaxf(m[2], h0 ? mw2 : 0.f);
            m[3] = fmaxf(m[3], mw0);
            m[4] = fmaxf(m[4], mall);
            m[5] = fmaxf(m[5], mw2);
            m[6] = fmaxf(m[6], h2 ? mw0 : 0.f);
            m[7] = fmaxf(m[7], h2 ? mall : 0.f);
            m[8] = fmaxf(m[8], h2 ? mw2 : 0.f);
        }
#pragma unroll
        for (int i = 0; i < 9; ++i)
            for (int off = 32; off; off >>= 1)
                m[i] = fmaxf(m[i], __shfl_down(m[i], off));
        __shared__ float sred[4][9];
        if (lane == 0)
#pragma unroll
            for (int i = 0; i < 9; ++i) sred[wid][i] = m[i];
        __syncthreads();
        if (tid < 9) {
            float mm = fmaxf(fmaxf(sred[0][tid], sred[1][tid]),
                             fmaxf(sred[2][tid], sred[3][tid]));
            atomicMax((int*)(wsf + WS_ACT + c * 9 + tid), __float_as_int(mm));
        }
    } else {
        const int k = (blockIdx.x - 1024) * 4 + wid;
        float m = fmaxf(fabsf(w[lane * KSIZE + k]), fabsf(w[(lane + 64) * KSIZE + k]));
        for (int off = 32; off; off >>= 1) m = fmaxf(m, __shfl_down(m, off));
        if (lane == 0) wsf[WS_WSC + k] = m;
    }
}

// ---------------------------------------------------------------------------
// Kernel 2: scale + weight quantize -> int8, pre-swizzled (unchanged — validated R3/R4).
// ---------------------------------------------------------------------------
__global__ __launch_bounds__(576) void k_scale_wq(const float* __restrict__ w,
                                                  float* __restrict__ wsf,
                                                  char* __restrict__ wq_s) {
    __shared__ float ls[576];
    __shared__ float redA[9], redB[9];
    const int t = threadIdx.x, o = blockIdx.x;
    const int lane = t & 63, wid = t >> 6;
    const float a = wsf[WS_ACT + t];
    const float wv = wsf[WS_WSC + t];
    float s = sqrtf(a) / sqrtf(wv);
    if (s == 0.f) s = 1.f;
    ls[t] = s;
    float v1 = a / s;
    float v2 = wv * s;
    for (int off = 32; off; off >>= 1) {
        v1 = fmaxf(v1, __shfl_down(v1, off));
        v2 = fmaxf(v2, __shfl_down(v2, off));
    }
    if (lane == 0) { redA[wid] = v1; redB[wid] = v2; }
    __syncthreads();
    float ax = redA[0], aw = redB[0];
#pragma unroll
    for (int i = 1; i < 9; ++i) { ax = fmaxf(ax, redA[i]); aw = fmaxf(aw, redB[i]); }
    const float sx = ax > 0.f ? ax / 127.f : 1.f;
    const float sw = aw > 0.f ? aw / 127.f : 1.f;
    const int r = t >> 6, c = t & 63, ko = c * 9 + r;
    float q = rintf((w[o * KSIZE + ko] * ls[ko]) / sw);
    q = fminf(127.f, fmaxf(-127.f, q));
    const int qi = (int)q;
    const int fc = c >> 4;
    wq_s[r * 8192 + o * 64 + ((fc ^ SWZ(o)) << 4) + (c & 15)] = (char)qi;
    if (o == 0) {
        wsf[WS_XMUL + t] = 1.0f / (ls[ko] * sx);   // [r][c] layout
        if (t == 0) wsf[WS_SXSW] = sx * sw;
    }
}

// ---------------------------------------------------------------------------
// Kernel 3: barrier-free i8 implicit-GEMM conv, v3.
// Block = (b, oh-pair): 512 threads = 8 waves. Waves 0-3 own oh, waves 4-7 own
// oh+1. Wave tile 32ow x 128oc: TWO A-fragments share every B ds_read_b128
// (8 reads -> 16 MFMA, halving the LDS pipe time vs v2). Half the blocks of
// v2 -> half the 72KB weight-staging traffic and half the prologue barriers.
// Per chunk per thread: 32 coalesced dword loads, 32 one-FMA magic quantizes,
// 6 v_perm packs/8el, 8 conflict-free ds_read_b128 of B, 16 MFMA.
// h-skip is wave-uniform (no barriers in the loop, divergence across halves free).
// ---------------------------------------------------------------------------
__global__ __launch_bounds__(512, 4) void k_gemm(const float* __restrict__ in,
                                                 const char* __restrict__ wq_s,
                                                 const float* __restrict__ wsf,
                                                 float* __restrict__ out) {
    __shared__ int4v Bl4[4608];        // 73728 B: 9 planes of [o=128][c=64] i8
    __shared__ float xml[576];
    char* Bl = (char*)Bl4;

    const int tid = threadIdx.x, lane = tid & 63, w = tid >> 6;
    // XCD swizzle: each XCD owns a 16-row oh band per batch (L2 input reuse).
    const int xcd = blockIdx.x & 7, idx = blockIdx.x >> 3;
    const int ohp = idx & 7;               // oh-pair index inside band
    const int b = idx >> 3;                // batch
    const int wh = w >> 2, wm = w & 3;     // oh-half, ow-quarter
    const int oh = xcd * 16 + ohp * 2 + wh;
    const int l15 = lane & 15, fsel = lane >> 4;
    const int ow0 = wm * 32 + l15;         // frag0 M index; frag1 = ow0 + 16

    // ---- prologue staging (only barrier in the kernel) ----
#pragma unroll
    for (int i = 0; i < 9; ++i)
        async_cp16(wq_s + i * 8192 + tid * 16, Bl + i * 8192 + tid * 16);
    if (tid < 144)
        ((float4v*)xml)[tid] = ((const float4v*)(wsf + WS_XMUL))[tid];
    __syncthreads();

    const float* pb = in + ((size_t)b * CIN + fsel * 16) * (HW * HW);

    int4v acc0[8], acc1[8];
#pragma unroll
    for (int nt = 0; nt < 8; ++nt) {
        acc0[nt] = (int4v){0, 0, 0, 0};
        acc1[nt] = (int4v){0, 0, 0, 0};
    }

#pragma unroll
    for (int r = 0; r < 9; ++r) {
        const int kh = r / 3, kw = r - 3 * kh;
        const int h = oh + kh - 1;
        if (h >= 0 && h < HW) {            // wave-uniform: skip whole chunk
            const int iw0 = ow0 + kw - 1;  // frag0 input col
            const int iw1 = iw0 + 16;      // frag1 input col
            int iwc0 = iw0, iwc1 = iw1;
            if (kw == 0) iwc0 = iw0 < 0 ? 0 : iw0;       // frag1 never < 0
            if (kw == 2) iwc1 = iw1 > 127 ? 127 : iw1;   // frag0 never > 127
            // ---- A loads: lanes 0..15 contiguous iw -> coalesced dwords ----
            const float* p0 = pb + h * HW + iwc0;
            const float* p1 = pb + h * HW + iwc1;
            float v0[16], v1[16];
#pragma unroll
            for (int j = 0; j < 16; ++j) {
                v0[j] = p0[j * (HW * HW)];
                v1[j] = p1[j * (HW * HW)];
            }
            // ---- quantize both frags: single fma (magic bias) + 3 perm/4el;
            //      xq loaded per-group to bound register pressure ----
            const float* xp = xml + r * 64 + (fsel << 4);
            uint pk0[4], pk1[4];
#pragma unroll
            for (int d = 0; d < 4; ++d) {
                const float4v xq = *(const float4v*)(xp + d * 4);
                uint u0[4], u1[4];
#pragma unroll
                for (int j2 = 0; j2 < 4; ++j2) {
                    u0[j2] = __float_as_uint(fmaf(v0[d * 4 + j2], xq[j2], MAGIC));
                    u1[j2] = __float_as_uint(fmaf(v1[d * 4 + j2], xq[j2], MAGIC));
                }
                const uint a01 = __builtin_amdgcn_perm(u0[1], u0[0], 0x0C0C0400u);
                const uint a23 = __builtin_amdgcn_perm(u0[3], u0[2], 0x0C0C0400u);
                pk0[d] = __builtin_amdgcn_perm(a23, a01, 0x05040100u);
                const uint b01 = __builtin_amdgcn_perm(u1[1], u1[0], 0x0C0C0400u);
                const uint b23 = __builtin_amdgcn_perm(u1[3], u1[2], 0x0C0C0400u);
                pk1[d] = __builtin_amdgcn_perm(b23, b01, 0x05040100u);
            }
            int4v af0, af1;
            if (kw == 0) {                 // only frag0's lane 0 can be OOB-low
                const uint msk = ((unsigned)iw0 < 128u) ? 0xFFFFFFFFu : 0u;
                af0 = (int4v){(int)(pk0[0] & msk), (int)(pk0[1] & msk),
                              (int)(pk0[2] & msk), (int)(pk0[3] & msk)};
                af1 = (int4v){(int)pk1[0], (int)pk1[1], (int)pk1[2], (int)pk1[3]};
            } else if (kw == 2) {          // only frag1's lane 15 can be OOB-high
                const uint msk = ((unsigned)iw1 < 128u) ? 0xFFFFFFFFu : 0u;
                af0 = (int4v){(int)pk0[0], (int)pk0[1], (int)pk0[2], (int)pk0[3]};
                af1 = (int4v){(int)(pk1[0] & msk), (int)(pk1[1] & msk),
                              (int)(pk1[2] & msk), (int)(pk1[3] & msk)};
            } else {
                af0 = (int4v){(int)pk0[0], (int)pk0[1], (int)pk0[2], (int)pk0[3]};
                af1 = (int4v){(int)pk1[0], (int)pk1[1], (int)pk1[2], (int)pk1[3]};
            }
            // ---- B frags (conflict-free swizzle), each feeds 2 MFMA ----
#pragma unroll
            for (int nt = 0; nt < 8; ++nt) {
                const int br = nt * 16 + l15;
                const int4v bf = *(const int4v*)(Bl + r * 8192 + br * 64 +
                                                 ((fsel ^ SWZ(br)) << 4));
                acc0[nt] = __builtin_amdgcn_mfma_i32_16x16x64_i8(af0, bf, acc0[nt], 0, 0, 0);
                acc1[nt] = __builtin_amdgcn_mfma_i32_16x16x64_i8(af1, bf, acc1[nt], 0, 0, 0);
            }
        }
    }

    // ---- epilogue: row=(lane>>4)*4+reg -> ow, col=lane&15 -> o ----
    const float sxsw = wsf[WS_SXSW];
    const int owp = wm * 32 + (fsel << 2);
#pragma unroll
    for (int nt = 0; nt < 8; ++nt) {
        const int o = nt * 16 + l15;
        float4v rv0, rv1;
#pragma unroll
        for (int q = 0; q < 4; ++q) {
            rv0[q] = (float)acc0[nt][q] * sxsw;
            rv1[q] = (float)acc1[nt][q] * sxsw;
        }
        float* po = out + ((size_t)(b * OC + o) * HW + oh) * HW;
        *(float4v*)(po + owp) = rv0;
        *(float4v*)(po + owp + 16) = rv1;
    }
}

// ---------------------------------------------------------------------------
extern "C" void kernel_launch(void* const* d_in, const int* in_sizes, int n_in,
                              void* d_out, int out_size, void* d_ws, size_t ws_size,
                              hipStream_t stream) {
    const float* in = (const float*)d_in[0];   // (16, 64, 128, 128) fp32
    const float* wt = (const float*)d_in[1];   // (128, 64, 3, 3) fp32
    float* out = (float*)d_out;                // (16, 128, 128, 128) fp32
    float* wsf = (float*)d_ws;
    char* wq_s = (char*)d_ws + WS_WQ_BYTE_OFF;

    k_absmax<<<dim3(1024 + 144), dim3(256), 0, stream>>>(in, wt, wsf);
    k_scale_wq<<<dim3(128), dim3(576), 0, stream>>>(wt, wsf, wq_s);
    k_gemm<<<dim3(BATCH * HW / 2), dim3(512), 0, stream>>>(in, wq_s, wsf, out);
}